// Round 1
// baseline (68.829 us; speedup 1.0000x reference)
//
#include <hip/hip_runtime.h>
#include <math.h>

#define SCALE 8
#define PSZ 32

// ---- constant twiddles: W_32^k = cos(2pi k/32) - i sin(2pi k/32), k=0..15 ----
__device__ constexpr float C32[16] = {
     1.000000000000000f,  0.980785280403230f,  0.923879532511287f,  0.831469612302545f,
     0.707106781186548f,  0.555570233019602f,  0.382683432365090f,  0.195090322016128f,
     0.000000000000000f, -0.195090322016128f, -0.382683432365090f, -0.555570233019602f,
    -0.707106781186548f, -0.831469612302545f, -0.923879532511287f, -0.980785280403230f };
__device__ constexpr float S32[16] = {
     0.000000000000000f,  0.195090322016128f,  0.382683432365090f,  0.555570233019602f,
     0.707106781186548f,  0.831469612302545f,  0.923879532511287f,  0.980785280403230f,
     1.000000000000000f,  0.980785280403230f,  0.923879532511287f,  0.831469612302545f,
     0.707106781186548f,  0.555570233019602f,  0.382683432365090f,  0.195090322016128f };

__device__ __forceinline__ constexpr int brev5(int i) {
    return ((i & 1) << 4) | ((i & 2) << 2) | (i & 4) | ((i & 8) >> 2) | ((i & 16) >> 4);
}

// in-place 32-point radix-2 DIT FFT, fully unrolled (all indices compile-time)
__device__ __forceinline__ void fft32(float re[PSZ], float im[PSZ]) {
    // bit-reversal permutation
#pragma unroll
    for (int i = 0; i < 32; ++i) {
        const int j = brev5(i);
        if (j > i) {
            float t = re[i]; re[i] = re[j]; re[j] = t;
            t = im[i]; im[i] = im[j]; im[j] = t;
        }
    }
    // 5 butterfly stages
#pragma unroll
    for (int s = 1; s <= 5; ++s) {
        const int m = 1 << s;
        const int h = m >> 1;
        const int tstep = 32 >> s;
#pragma unroll
        for (int k = 0; k < 32; k += m) {
#pragma unroll
            for (int j = 0; j < h; ++j) {
                const float wr = C32[j * tstep];
                const float wi = -S32[j * tstep];
                const int a = k + j;
                const int b = k + j + h;
                const float tr = wr * re[b] - wi * im[b];
                const float ti = wr * im[b] + wi * re[b];
                re[b] = re[a] - tr; im[b] = im[a] - ti;
                re[a] = re[a] + tr; im[a] = im[a] + ti;
            }
        }
    }
}

// One 64-thread block handles 2 patches (one per 32-lane group).
// Lane r of its group owns patch-row r: loads it (gray fused), row-FFT in
// registers, LDS transpose (stride 33, conflict-free), column-FFT, masked
// log-power sum, 32-lane shuffle reduce.
__global__ __launch_bounds__(64) void hfdft_patch_kernel(
        const float* __restrict__ x, const float* __restrict__ w,
        float* __restrict__ out, int H, int W, int mat_h, int mat_w) {
    __shared__ float tr[2][PSZ * 33];

    const int lane = threadIdx.x;
    const int sub = lane >> 5;        // which patch within the block
    const int r = lane & 31;          // patch row owned by this lane
    const int p = blockIdx.x * 2 + sub;
    const int total = mat_h * mat_w;
    const bool active = (p < total);
    const int ph = active ? (p / mat_w) : 0;
    const int pw = active ? (p % mat_w) : 0;

    const float w0 = w[0], w1 = w[1], w2 = w[2];
    const long long HW = (long long)H * W;
    const int base = (ph * SCALE + r) * W + pw * SCALE;

    float re[PSZ], im[PSZ];
#pragma unroll
    for (int i = 0; i < PSZ; ++i) im[i] = 0.0f;

    if ((W & 3) == 0) {
        const float4* a4 = reinterpret_cast<const float4*>(x + base);
        const float4* b4 = reinterpret_cast<const float4*>(x + HW + base);
        const float4* c4 = reinterpret_cast<const float4*>(x + 2 * HW + base);
#pragma unroll
        for (int q = 0; q < 8; ++q) {
            const float4 a = a4[q], b = b4[q], c = c4[q];
            re[4 * q + 0] = w0 * a.x + w1 * b.x + w2 * c.x;
            re[4 * q + 1] = w0 * a.y + w1 * b.y + w2 * c.y;
            re[4 * q + 2] = w0 * a.z + w1 * b.z + w2 * c.z;
            re[4 * q + 3] = w0 * a.w + w1 * b.w + w2 * c.w;
        }
    } else {
#pragma unroll
        for (int i = 0; i < PSZ; ++i) {
            re[i] = w0 * x[base + i] + w1 * x[HW + base + i] + w2 * x[2 * HW + base + i];
        }
    }

    // ---- row FFT ----
    fft32(re, im);

    // ---- transpose via LDS (stride 33 pad, re then im reusing the buffer) ----
    float cre[PSZ], cim[PSZ];
#pragma unroll
    for (int i = 0; i < PSZ; ++i) tr[sub][r * 33 + i] = re[i];
    __syncthreads();
#pragma unroll
    for (int i = 0; i < PSZ; ++i) cre[i] = tr[sub][i * 33 + r];
    __syncthreads();
#pragma unroll
    for (int i = 0; i < PSZ; ++i) tr[sub][r * 33 + i] = im[i];
    __syncthreads();
#pragma unroll
    for (int i = 0; i < PSZ; ++i) cim[i] = tr[sub][i * 33 + r];

    // ---- column FFT: lane r now owns column-frequency kc = r ----
    fft32(cre, cim);

    // ---- masked log-power sum ----
    // include (kr, kc) iff kr in [7,24]  OR  kc in [7,24]
    const bool fullcol = (r >= 7 && r <= 24);
    float s = 0.0f;
#pragma unroll
    for (int kr = 0; kr < 32; ++kr) {
        const float pwv = cre[kr] * cre[kr] + cim[kr] * cim[kr] + 1.0f;
        const float lp = __logf(pwv);
        if (kr >= 7 && kr <= 24) {
            s += lp;                       // compile-time: always included
        } else {
            s += fullcol ? lp : 0.0f;      // uniform per-lane predicate
        }
    }

    // ---- reduce across the 32-lane group ----
#pragma unroll
    for (int off = 16; off >= 1; off >>= 1) s += __shfl_xor(s, off, 32);

    if (r == 0 && active) out[p] = s;
}

__global__ __launch_bounds__(256) void max_kernel(
        const float* __restrict__ sums, int n, float* __restrict__ mx) {
    __shared__ float sm[4];
    float m = 0.0f;  // sums are >= 0 (log of >=1 values)
    for (int i = threadIdx.x; i < n; i += 256) m = fmaxf(m, sums[i]);
#pragma unroll
    for (int off = 32; off >= 1; off >>= 1) m = fmaxf(m, __shfl_xor(m, off, 64));
    if ((threadIdx.x & 63) == 0) sm[threadIdx.x >> 6] = m;
    __syncthreads();
    if (threadIdx.x == 0) {
        m = fmaxf(fmaxf(sm[0], sm[1]), fmaxf(sm[2], sm[3]));
        mx[0] = m;
    }
}

__global__ __launch_bounds__(256) void norm_kernel(
        float* __restrict__ out, int n, const float* __restrict__ mx) {
    const int i = blockIdx.x * 256 + threadIdx.x;
    if (i < n) out[i] = out[i] / mx[0];
}

extern "C" void kernel_launch(void* const* d_in, const int* in_sizes, int n_in,
                              void* d_out, int out_size, void* d_ws, size_t ws_size,
                              hipStream_t stream) {
    const float* x = (const float*)d_in[0];
    const float* w = (const float*)d_in[1];
    float* out = (float*)d_out;
    float* maxbuf = (float*)d_ws;

    // derive geometry on host (no device reads): x is (1,3,H,W) with H==W,
    // out is (1,1,mat,mat)
    const int HW = in_sizes[0] / 3;
    const int H = (int)(sqrt((double)HW) + 0.5);
    const int W = H;
    const int mat = (int)(sqrt((double)out_size) + 0.5);
    const int total = mat * mat;

    const int blocksA = (total + 1) / 2;
    hipLaunchKernelGGL(hfdft_patch_kernel, dim3(blocksA), dim3(64), 0, stream,
                       x, w, out, H, W, mat, mat);
    hipLaunchKernelGGL(max_kernel, dim3(1), dim3(256), 0, stream, out, total, maxbuf);
    hipLaunchKernelGGL(norm_kernel, dim3((total + 255) / 256), dim3(256), 0, stream,
                       out, total, maxbuf);
}

// Round 2
// 44.117 us; speedup vs baseline: 1.5601x; 1.5601x over previous
//
#include <hip/hip_runtime.h>
#include <math.h>

#define SCALE 8
#define PSZ 32

// ---- constant twiddles: W_32^k = cos(2pi k/32) - i sin(2pi k/32), k=0..15 ----
__device__ constexpr float C32[16] = {
     1.000000000000000f,  0.980785280403230f,  0.923879532511287f,  0.831469612302545f,
     0.707106781186548f,  0.555570233019602f,  0.382683432365090f,  0.195090322016128f,
     0.000000000000000f, -0.195090322016128f, -0.382683432365090f, -0.555570233019602f,
    -0.707106781186548f, -0.831469612302545f, -0.923879532511287f, -0.980785280403230f };
__device__ constexpr float S32[16] = {
     0.000000000000000f,  0.195090322016128f,  0.382683432365090f,  0.555570233019602f,
     0.707106781186548f,  0.831469612302545f,  0.923879532511287f,  0.980785280403230f,
     1.000000000000000f,  0.980785280403230f,  0.923879532511287f,  0.831469612302545f,
     0.707106781186548f,  0.555570233019602f,  0.382683432365090f,  0.195090322016128f };

__device__ __forceinline__ constexpr int brev5(int i) {
    return ((i & 1) << 4) | ((i & 2) << 2) | (i & 4) | ((i & 8) >> 2) | ((i & 16) >> 4);
}

// in-place 32-point radix-2 DIT FFT, fully unrolled (all indices compile-time)
__device__ __forceinline__ void fft32(float re[PSZ], float im[PSZ]) {
#pragma unroll
    for (int i = 0; i < 32; ++i) {
        const int j = brev5(i);
        if (j > i) {
            float t = re[i]; re[i] = re[j]; re[j] = t;
            t = im[i]; im[i] = im[j]; im[j] = t;
        }
    }
#pragma unroll
    for (int s = 1; s <= 5; ++s) {
        const int m = 1 << s;
        const int h = m >> 1;
        const int tstep = 32 >> s;
#pragma unroll
        for (int k = 0; k < 32; k += m) {
#pragma unroll
            for (int j = 0; j < h; ++j) {
                const float wr = C32[j * tstep];
                const float wi = -S32[j * tstep];
                const int a = k + j;
                const int b = k + j + h;
                const float tr = wr * re[b] - wi * im[b];
                const float ti = wr * im[b] + wi * re[b];
                re[b] = re[a] - tr; im[b] = im[a] - ti;
                re[a] = re[a] + tr; im[a] = im[a] + ti;
            }
        }
    }
}

// bf16x2 pack/unpack (round-half-up via +0x8000)
__device__ __forceinline__ unsigned pack_bf2(float hi, float lo) {
    const unsigned uh = __float_as_uint(hi) + 0x8000u;
    const unsigned ul = __float_as_uint(lo) + 0x8000u;
    return (uh & 0xFFFF0000u) | (ul >> 16);
}
__device__ __forceinline__ float bf_hi(unsigned u) { return __uint_as_float(u & 0xFFFF0000u); }
__device__ __forceinline__ float bf_lo(unsigned u) { return __uint_as_float(u << 16); }

// One 64-thread block = 4 patches.
// Row stage: lane (g=lane>>5, r=lane&31) packs row r of patches (2g, 2g+1) as
// a + i*b -> ONE complex FFT32 -> per-lane unpack to the two real-row spectra
// (only k=0..16 needed; cols 0 & 16 are real and share slot 0 packed as
// (c0, c16)). Spectra stored in LDS as bf16x2, layout [patch][slot*33 + row]
// (2-way bank aliasing only = free).
// Col stage: lane (pl=lane>>4, slot=lane&15): 15 complex column FFTs + 1
// packed real-pair column FFT per patch; masked log-power sums use
// compile-time Hermitian mirror weights {0,1,2}. 16-lane shuffle reduce.
__global__ __launch_bounds__(64) void hfdft_patch_kernel(
        const float* __restrict__ x, const float* __restrict__ w,
        float* __restrict__ out, int H, int W, int mat_h, int mat_w) {
    __shared__ unsigned cb[4 * 528];   // 4 patches * 16 slots * stride 33 (u32 of bf16x2)

    const int lane = threadIdx.x;
    const int total = mat_h * mat_w;
    const float w0 = w[0], w1 = w[1], w2 = w[2];
    const long long HW = (long long)H * W;

    // ================= row stage =================
    {
        const int g = lane >> 5, r = lane & 31;
        int pA = blockIdx.x * 4 + 2 * g;
        if (pA > total - 1) pA = total - 1;
        int pB = pA + 1; if (pB > total - 1) pB = total - 1;
        const int phA = pA / mat_w, pwA = pA % mat_w;
        const int phB = pB / mat_w, pwB = pB % mat_w;
        const bool adj = (phA == phB) && (pwB == pwA + 1);

        float re[PSZ], im[PSZ];
        if (adj && ((W & 3) == 0)) {
            // shared 40-px window: patch B starts SCALE=8 px right of A
            const int base = (phA * SCALE + r) * W + pwA * SCALE;
            const float4* a4 = reinterpret_cast<const float4*>(x + base);
            const float4* b4 = reinterpret_cast<const float4*>(x + HW + base);
            const float4* c4 = reinterpret_cast<const float4*>(x + 2 * HW + base);
            float win[40];
#pragma unroll
            for (int q = 0; q < 10; ++q) {
                const float4 a = a4[q], b = b4[q], c = c4[q];
                win[4 * q + 0] = w0 * a.x + w1 * b.x + w2 * c.x;
                win[4 * q + 1] = w0 * a.y + w1 * b.y + w2 * c.y;
                win[4 * q + 2] = w0 * a.z + w1 * b.z + w2 * c.z;
                win[4 * q + 3] = w0 * a.w + w1 * b.w + w2 * c.w;
            }
#pragma unroll
            for (int i = 0; i < PSZ; ++i) { re[i] = win[i]; im[i] = win[i + 8]; }
        } else {
            const int baseA = (phA * SCALE + r) * W + pwA * SCALE;
            const int baseB = (phB * SCALE + r) * W + pwB * SCALE;
#pragma unroll
            for (int i = 0; i < PSZ; ++i) {
                re[i] = w0 * x[baseA + i] + w1 * x[HW + baseA + i] + w2 * x[2 * HW + baseA + i];
                im[i] = w0 * x[baseB + i] + w1 * x[HW + baseB + i] + w2 * x[2 * HW + baseB + i];
            }
        }

        fft32(re, im);   // FFT of rowA + i*rowB

        // unpack the two real-row spectra; store k=0..16 (slot0 = (F(0),F(16)) both real)
        unsigned* cbA = cb + (2 * g) * 528;
        unsigned* cbB = cb + (2 * g + 1) * 528;
        cbA[r] = pack_bf2(re[0], re[16]);
        cbB[r] = pack_bf2(im[0], im[16]);
#pragma unroll
        for (int k = 1; k <= 15; ++k) {
            const int m = 32 - k;
            const float far_ = 0.5f * (re[k] + re[m]);
            const float fai_ = 0.5f * (im[k] - im[m]);
            const float fbr_ = 0.5f * (im[k] + im[m]);
            const float fbi_ = 0.5f * (re[m] - re[k]);
            cbA[k * 33 + r] = pack_bf2(far_, fai_);
            cbB[k * 33 + r] = pack_bf2(fbr_, fbi_);
        }
    }

    __syncthreads();

    // ================= column stage =================
    {
        const int pl = lane >> 4, slot = lane & 15;
        const int p = blockIdx.x * 4 + pl;
        const unsigned* cbp = cb + pl * 528 + slot * 33;

        float cre[PSZ], cim[PSZ];
#pragma unroll
        for (int r2 = 0; r2 < PSZ; ++r2) {
            const unsigned u = cbp[r2];
            cre[r2] = bf_hi(u);
            cim[r2] = bf_lo(u);
        }

        fft32(cre, cim);

        float s = 0.0f;
        if (slot == 0) {
            // packed pair (col 0, col 16): unpack kr=0..16, Hermitian-in-kr weights
#pragma unroll
            for (int kr = 0; kr <= 16; ++kr) {
                const int m = (32 - kr) & 31;
                const float g0r = 0.5f * (cre[kr] + cre[m]);
                const float g0i = 0.5f * (cim[kr] - cim[m]);
                const float g1r = 0.5f * (cim[kr] + cim[m]);
                const float g1i = 0.5f * (cre[m] - cre[kr]);
                const float w0c = (kr >= 7 ? 1.0f : 0.0f) + ((kr >= 8 && kr <= 15) ? 1.0f : 0.0f);
                const float w16c = 1.0f + ((kr >= 1 && kr <= 15) ? 1.0f : 0.0f);
                if (w0c > 0.0f)
                    s = fmaf(w0c, __logf(g0r * g0r + g0i * g0i + 1.0f), s);
                s = fmaf(w16c, __logf(g1r * g1r + g1i * g1i + 1.0f), s);
            }
        } else {
            // column kc=slot (1..15) + its mirror column 32-slot via weights
            const float b1f = (slot >= 7) ? 1.0f : 0.0f;   // base mask full column
            const float m1f = (slot >= 8) ? 1.0f : 0.0f;   // mirror column full
#pragma unroll
            for (int kr = 0; kr < 32; ++kr) {
                const float lp = __logf(cre[kr] * cre[kr] + cim[kr] * cim[kr] + 1.0f);
                float wgt;
                if (kr >= 8 && kr <= 24)      wgt = 2.0f;
                else if (kr == 7)             wgt = 1.0f + m1f;
                else if (kr == 25)            wgt = b1f + 1.0f;
                else                          wgt = b1f + m1f;
                if (!(kr >= 8 && kr <= 24))   s = fmaf(wgt, lp, s);
                else                          s = fmaf(2.0f, lp, s);
            }
        }

        // reduce across the 16 lanes of this patch
#pragma unroll
        for (int off = 8; off >= 1; off >>= 1) s += __shfl_xor(s, off, 16);
        if (slot == 0 && p < total) out[p] = s;
    }
}

__global__ __launch_bounds__(1024) void max_kernel(
        const float* __restrict__ sums, int n, float* __restrict__ mx) {
    __shared__ float sm[16];
    float m = 0.0f;  // sums are >= 0
    for (int i = threadIdx.x; i < n; i += 1024) m = fmaxf(m, sums[i]);
#pragma unroll
    for (int off = 32; off >= 1; off >>= 1) m = fmaxf(m, __shfl_xor(m, off, 64));
    if ((threadIdx.x & 63) == 0) sm[threadIdx.x >> 6] = m;
    __syncthreads();
    if (threadIdx.x == 0) {
#pragma unroll
        for (int i = 1; i < 16; ++i) m = fmaxf(m, sm[i]);
        mx[0] = m;
    }
}

__global__ __launch_bounds__(256) void norm_kernel(
        float* __restrict__ out, int n, const float* __restrict__ mx) {
    const int i = blockIdx.x * 256 + threadIdx.x;
    if (i < n) out[i] = out[i] / mx[0];
}

extern "C" void kernel_launch(void* const* d_in, const int* in_sizes, int n_in,
                              void* d_out, int out_size, void* d_ws, size_t ws_size,
                              hipStream_t stream) {
    const float* x = (const float*)d_in[0];
    const float* w = (const float*)d_in[1];
    float* out = (float*)d_out;
    float* maxbuf = (float*)d_ws;

    const int HW = in_sizes[0] / 3;
    const int H = (int)(sqrt((double)HW) + 0.5);
    const int W = H;
    const int mat = (int)(sqrt((double)out_size) + 0.5);
    const int total = mat * mat;

    const int blocksA = (total + 3) / 4;
    hipLaunchKernelGGL(hfdft_patch_kernel, dim3(blocksA), dim3(64), 0, stream,
                       x, w, out, H, W, mat, mat);
    hipLaunchKernelGGL(max_kernel, dim3(1), dim3(1024), 0, stream, out, total, maxbuf);
    hipLaunchKernelGGL(norm_kernel, dim3((total + 255) / 256), dim3(256), 0, stream,
                       out, total, maxbuf);
}